// Round 4
// baseline (129.208 us; speedup 1.0000x reference)
//
#include <hip/hip_runtime.h>

typedef float    f32x4  __attribute__((ext_vector_type(4)));
typedef __bf16   bf16x8 __attribute__((ext_vector_type(8)));
typedef unsigned short u16;
typedef unsigned short u16x8 __attribute__((ext_vector_type(8)));
typedef int      i32x4  __attribute__((ext_vector_type(4)));

#define NN   8192
#define FIN  512
#define FOUT 64
#define LOG2E 1.4426950408889634f

#if __has_builtin(__builtin_amdgcn_exp2f)
#define EXP2F(x) __builtin_amdgcn_exp2f(x)
#else
#define EXP2F(x) exp2f(x)
#endif

__device__ __forceinline__ u16 f2bf(float f) {          // f32 -> bf16 RNE
    unsigned int u = __float_as_uint(f);
    u += 0x7FFFu + ((u >> 16) & 1u);
    return (u16)(u >> 16);
}
__device__ __forceinline__ float bf2f(u16 b) {
    return __uint_as_float(((unsigned int)b) << 16);
}

// ---------------------------------------------------------------------------
// K0: W (512x64 f32) -> WT_hi/WT_lo (64x512 bf16, transposed hi/lo split)
// ---------------------------------------------------------------------------
__global__ __launch_bounds__(256) void k_wt(const float* __restrict__ W,
                                            u16* __restrict__ wt_hi,
                                            u16* __restrict__ wt_lo) {
    int t = blockIdx.x * 256 + threadIdx.x;   // 0..32767
    int k = t >> 6, c = t & 63;
    float w = W[t];                            // W[k*64+c]
    u16 h = f2bf(w);
    wt_hi[c * FIN + k] = h;
    wt_lo[c * FIN + k] = f2bf(w - bf2f(h));
}

// ---------------------------------------------------------------------------
// K1: z = input @ W (3-term bf16 MFMA split ~ f32-exact), then:
//   - zt (bf16, TILED transposed layout [j/8][c<64][j&7]) from accumulators
//   - s1p = (z@a1)*log2e, s2p = (z@a2)*log2e from f32 accumulators
// grid 512 x 128thr: block = one 16-row m-tile, 2 waves K-split.
// ---------------------------------------------------------------------------
__global__ __launch_bounds__(128) void k_zgemm(
        const float* __restrict__ in, const u16* __restrict__ wt_hi,
        const u16* __restrict__ wt_lo, const float* __restrict__ a,
        u16* __restrict__ zt, float* __restrict__ s1p, float* __restrict__ s2p)
{
    __shared__ f32x4 xch[4][64];
    const int wv = threadIdx.x >> 6;
    const int l  = threadIdx.x & 63;
    const int lr = l & 15, lk = l >> 4;
    const int row_base = blockIdx.x * 16;

    f32x4 acc[4] = {};
    const float* inrow = in + (size_t)(row_base + lr) * FIN;

    for (int ks = wv * 8; ks < wv * 8 + 8; ++ks) {
        const int k0 = ks * 32 + lk * 8;
        const f32x4 v0 = *(const f32x4*)(inrow + k0);
        const f32x4 v1 = *(const f32x4*)(inrow + k0 + 4);
        u16x8 hv, lv;
#pragma unroll
        for (int i = 0; i < 4; ++i) {
            u16 h = f2bf(v0[i]); hv[i] = h; lv[i] = f2bf(v0[i] - bf2f(h));
        }
#pragma unroll
        for (int i = 0; i < 4; ++i) {
            u16 h = f2bf(v1[i]); hv[4 + i] = h; lv[4 + i] = f2bf(v1[i] - bf2f(h));
        }
        const bf16x8 ahi = __builtin_bit_cast(bf16x8, hv);
        const bf16x8 alo = __builtin_bit_cast(bf16x8, lv);
#pragma unroll
        for (int nt = 0; nt < 4; ++nt) {
            const int wrow = nt * 16 + lr;
            const bf16x8 bh = __builtin_bit_cast(bf16x8, *(const u16x8*)(wt_hi + (size_t)wrow * FIN + k0));
            const bf16x8 bl = __builtin_bit_cast(bf16x8, *(const u16x8*)(wt_lo + (size_t)wrow * FIN + k0));
            acc[nt] = __builtin_amdgcn_mfma_f32_16x16x32_bf16(ahi, bh, acc[nt], 0, 0, 0);
            acc[nt] = __builtin_amdgcn_mfma_f32_16x16x32_bf16(alo, bh, acc[nt], 0, 0, 0);
            acc[nt] = __builtin_amdgcn_mfma_f32_16x16x32_bf16(ahi, bl, acc[nt], 0, 0, 0);
        }
    }

    if (wv == 1) {
#pragma unroll
        for (int nt = 0; nt < 4; ++nt) xch[nt][l] = acc[nt];
    }
    __syncthreads();
    if (wv == 1) return;
#pragma unroll
    for (int nt = 0; nt < 4; ++nt) acc[nt] += xch[nt][l];

    // store zt (bf16, tiled transposed): elem (j, c) -> zt[(j>>3)*512 + c*8 + (j&7)]
#pragma unroll
    for (int nt = 0; nt < 4; ++nt)
#pragma unroll
        for (int r = 0; r < 4; ++r) {
            const int j = row_base + lk * 4 + r;
            const int c = nt * 16 + lr;
            zt[(size_t)(j >> 3) * 512 + c * 8 + (j & 7)] = f2bf(acc[nt][r]);
        }

    // s1/s2 from exact accumulators
    float a1c[4], a2c[4];
#pragma unroll
    for (int nt = 0; nt < 4; ++nt) {
        a1c[nt] = a[nt * 16 + lr];
        a2c[nt] = a[64 + nt * 16 + lr];
    }
#pragma unroll
    for (int r = 0; r < 4; ++r) {
        float s1 = 0.f, s2 = 0.f;
#pragma unroll
        for (int nt = 0; nt < 4; ++nt) {
            s1 += acc[nt][r] * a1c[nt];
            s2 += acc[nt][r] * a2c[nt];
        }
#pragma unroll
        for (int m = 1; m <= 8; m <<= 1) {
            s1 += __shfl_xor(s1, m, 64);
            s2 += __shfl_xor(s2, m, 64);
        }
        if (lr == 0) {
            s1p[row_base + lk * 4 + r] = s1 * LOG2E;
            s2p[row_base + lk * 4 + r] = s2 * LOG2E;
        }
    }
}

// ---------------------------------------------------------------------------
// K3: fused masked-softmax attention + PV.
// 256 blocks x 512 thr (8 waves), 2 blocks/CU (VGPR<=128 via launch_bounds).
// Block = 32 rows. Wave wv owns j-slice [wv*32, wv*32+32) of each 256-tile.
// Per body N (FIFO-ordered, no LDS/barriers in loop):
//   [LOADZ z(N+1)] [PHA(N): waits s2(N), leaves adj(N+1)/z(N+1) in flight]
//   [LOADS2 s2(N+1) -> same regs] [LOADA adj(N+2)] [MFMA(N): waits z(N)]
// adj flight ~2 bodies; s2/z ~1 body (L2). All state in NAMED registers.
// ---------------------------------------------------------------------------
#define LOADZ(Z0, Z1, Z2, Z3, jn) do {                                        \
    const u16* _zb = zq + (size_t)(((jn) + jb) >> 3) * 512;                   \
    Z0 = *(const u16x8*)(_zb +   0);                                          \
    Z1 = *(const u16x8*)(_zb + 128);                                          \
    Z2 = *(const u16x8*)(_zb + 256);                                          \
    Z3 = *(const u16x8*)(_zb + 384); } while (0)

#define LOADA(P00, P01, P10, P11, jn) do {                                    \
    P00 = __builtin_nontemporal_load((const i32x4*)(ar0 + (jn)));             \
    P01 = __builtin_nontemporal_load((const i32x4*)(ar0 + (jn) + 4));         \
    P10 = __builtin_nontemporal_load((const i32x4*)(ar1 + (jn)));             \
    P11 = __builtin_nontemporal_load((const i32x4*)(ar1 + (jn) + 4)); } while (0)

#define LOADS2(jn) do {                                                       \
    sS0 = *(const f32x4*)(s2r + (jn));                                        \
    sS1 = *(const f32x4*)(s2r + (jn) + 4); } while (0)

#define PHA(WF, P0, P1, S1R, DD) do {                                         \
    _Pragma("unroll")                                                         \
    for (int i = 0; i < 4; ++i) {                                             \
        const float y = (S1R) + sS0[i];                                       \
        float w = EXP2F(fmaxf(y, 0.2f * y));                                  \
        w = (P0[i] != 0) ? w : 0.0f;                                          \
        const __bf16 wb = (__bf16)w;                                          \
        WF[i] = wb; DD += (float)wb; }                                        \
    _Pragma("unroll")                                                         \
    for (int i = 0; i < 4; ++i) {                                             \
        const float y = (S1R) + sS1[i];                                       \
        float w = EXP2F(fmaxf(y, 0.2f * y));                                  \
        w = (P1[i] != 0) ? w : 0.0f;                                          \
        const __bf16 wb = (__bf16)w;                                          \
        WF[4 + i] = wb; DD += (float)wb; } } while (0)

#define MFMA8(WF0, WF1, Z0, Z1, Z2, Z3) do {                                  \
    acc00 = __builtin_amdgcn_mfma_f32_16x16x32_bf16(WF0, __builtin_bit_cast(bf16x8, Z0), acc00, 0, 0, 0); \
    acc01 = __builtin_amdgcn_mfma_f32_16x16x32_bf16(WF0, __builtin_bit_cast(bf16x8, Z1), acc01, 0, 0, 0); \
    acc02 = __builtin_amdgcn_mfma_f32_16x16x32_bf16(WF0, __builtin_bit_cast(bf16x8, Z2), acc02, 0, 0, 0); \
    acc03 = __builtin_amdgcn_mfma_f32_16x16x32_bf16(WF0, __builtin_bit_cast(bf16x8, Z3), acc03, 0, 0, 0); \
    acc10 = __builtin_amdgcn_mfma_f32_16x16x32_bf16(WF1, __builtin_bit_cast(bf16x8, Z0), acc10, 0, 0, 0); \
    acc11 = __builtin_amdgcn_mfma_f32_16x16x32_bf16(WF1, __builtin_bit_cast(bf16x8, Z1), acc11, 0, 0, 0); \
    acc12 = __builtin_amdgcn_mfma_f32_16x16x32_bf16(WF1, __builtin_bit_cast(bf16x8, Z2), acc12, 0, 0, 0); \
    acc13 = __builtin_amdgcn_mfma_f32_16x16x32_bf16(WF1, __builtin_bit_cast(bf16x8, Z3), acc13, 0, 0, 0); } while (0)

#define BODY(CZ0, CZ1, CZ2, CZ3, NZ0, NZ1, NZ2, NZ3,                          \
             P00, P01, P10, P11, jn, DO_Z, DO_S, DO_P) do {                   \
    if (DO_Z) LOADZ(NZ0, NZ1, NZ2, NZ3, (jn) + 256);                          \
    __builtin_amdgcn_sched_barrier(0);                                        \
    bf16x8 wf0, wf1;                                                          \
    PHA(wf0, P00, P01, s1r0, d0);                                             \
    PHA(wf1, P10, P11, s1r1, d1);                                             \
    __builtin_amdgcn_sched_barrier(0);                                        \
    if (DO_S) LOADS2((jn) + 256);                                             \
    if (DO_P) LOADA(P00, P01, P10, P11, (jn) + 512);                          \
    __builtin_amdgcn_sched_barrier(0);                                        \
    MFMA8(wf0, wf1, CZ0, CZ1, CZ2, CZ3); } while (0)

__global__ __launch_bounds__(512, 4) void k_attn(
        const int* __restrict__ adj, const u16* __restrict__ zt,
        const float* __restrict__ s1p, const float* __restrict__ s2p,
        const float* __restrict__ bias, float* __restrict__ out)
{
    __shared__ float apart[8][32][64];   // 64 KiB (epilogue only)
    __shared__ float dpart[8][4][32];    // 4 KiB

    const int t  = threadIdx.x;
    const int wv = t >> 6, l = t & 63;
    const int lr = l & 15, lk = l >> 4;
    const int row0 = blockIdx.x * 32;
    const int jb = wv * 32 + lk * 8;     // wave+lane j offset within 256-tile

    const float s1r0 = s1p[row0 + lr];
    const float s1r1 = s1p[row0 + 16 + lr];
    const int*   ar0 = adj + (size_t)(row0 + lr) * NN + jb;
    const int*   ar1 = ar0 + (size_t)16 * NN;
    const float* s2r = s2p + jb;
    const u16*   zq  = zt + lr * 8;      // + jgroup*512 + nt*128 at load time

    f32x4 acc00{}, acc01{}, acc02{}, acc03{};
    f32x4 acc10{}, acc11{}, acc12{}, acc13{};
    float d0 = 0.f, d1 = 0.f;

    u16x8 zU0, zU1, zU2, zU3, zV0, zV1, zV2, zV3;
    i32x4 pA00, pA01, pA10, pA11, pB00, pB01, pB10, pB11;
    f32x4 sS0, sS1;

    LOADS2(0);
    LOADZ(zU0, zU1, zU2, zU3, 0);
    LOADA(pA00, pA01, pA10, pA11, 0);
    LOADA(pB00, pB01, pB10, pB11, 256);

    for (int jt = 0; jt < 30; jt += 2) {
        const int jn = jt * 256;
        BODY(zU0, zU1, zU2, zU3, zV0, zV1, zV2, zV3,
             pA00, pA01, pA10, pA11, jn, 1, 1, 1);
        BODY(zV0, zV1, zV2, zV3, zU0, zU1, zU2, zU3,
             pB00, pB01, pB10, pB11, jn + 256, 1, 1, 1);
    }
    BODY(zU0, zU1, zU2, zU3, zV0, zV1, zV2, zV3,
         pA00, pA01, pA10, pA11, 30 * 256, 1, 1, 0);   // loads s2(31), z(31)
    BODY(zV0, zV1, zV2, zV3, zU0, zU1, zU2, zU3,
         pB00, pB01, pB10, pB11, 31 * 256, 0, 0, 0);

    // ---------------- epilogue: cross-wave j-slice reduction -----------------
    dpart[wv][lk][lr]      = d0;
    dpart[wv][lk][16 + lr] = d1;
#pragma unroll
    for (int r = 0; r < 4; ++r) {
        apart[wv][lk * 4 + r][ 0 + lr] = acc00[r];
        apart[wv][lk * 4 + r][16 + lr] = acc01[r];
        apart[wv][lk * 4 + r][32 + lr] = acc02[r];
        apart[wv][lk * 4 + r][48 + lr] = acc03[r];
        apart[wv][16 + lk * 4 + r][ 0 + lr] = acc10[r];
        apart[wv][16 + lk * 4 + r][16 + lr] = acc11[r];
        apart[wv][16 + lk * 4 + r][32 + lr] = acc12[r];
        apart[wv][16 + lk * 4 + r][48 + lr] = acc13[r];
    }
    __syncthreads();

    {
        const int r  = t >> 4;           // 0..31
        const int c0 = (t & 15) * 4;
        float den = 0.f;
#pragma unroll
        for (int q = 0; q < 32; ++q)
            den += dpart[q >> 2][q & 3][r];
        f32x4 val = {};
#pragma unroll
        for (int q = 0; q < 8; ++q)
            val += *(const f32x4*)&apart[q][r][c0];
        const f32x4 bv = *(const f32x4*)(bias + c0);
        const f32x4 o = val * (1.0f / den) + bv;
        *(f32x4*)(out + (size_t)(row0 + r) * FOUT + c0) = o;
    }
}

// ---------------------------------------------------------------------------
extern "C" void kernel_launch(void* const* d_in, const int* in_sizes, int n_in,
                              void* d_out, int out_size, void* d_ws, size_t ws_size,
                              hipStream_t stream) {
    const float* input = (const float*)d_in[0];
    const int*   adj   = (const int*)d_in[1];
    const float* W     = (const float*)d_in[2];
    const float* a     = (const float*)d_in[3];
    const float* bias  = (const float*)d_in[4];
    float* out = (float*)d_out;

    char* ws = (char*)d_ws;
    u16*   wt_hi = (u16*)ws;   ws += FIN * FOUT * sizeof(u16);
    u16*   wt_lo = (u16*)ws;   ws += FIN * FOUT * sizeof(u16);
    float* s1p   = (float*)ws; ws += NN * sizeof(float);
    float* s2p   = (float*)ws; ws += NN * sizeof(float);
    u16*   zt    = (u16*)ws;   ws += (size_t)NN * FOUT * sizeof(u16);

    k_wt   <<<dim3(128), dim3(256), 0, stream>>>(W, wt_hi, wt_lo);
    k_zgemm<<<dim3(512), dim3(128), 0, stream>>>(input, wt_hi, wt_lo, a, zt, s1p, s2p);
    k_attn <<<dim3(256), dim3(512), 0, stream>>>(adj, zt, s1p, s2p, bias, out);
}